// Round 3
// baseline (127.031 us; speedup 1.0000x reference)
//
#include <hip/hip_runtime.h>

// vol [2,160,192,160,1] f32, trf [2,160,192,160,3] f32
constexpr int B = 2, X = 160, Y = 192, Z = 160;
constexpr int N = B * X * Y * Z;   // 9,830,400
constexpr int VPT = 4;             // voxels per thread (consecutive z)
constexpr int NT = N / VPT;        // Z divisible by 4 -> no tail

typedef float f32x4 __attribute__((ext_vector_type(4)));

__global__ __launch_bounds__(256) void warp_kernel(
    const float* __restrict__ vol,
    const float* __restrict__ trf,
    float* __restrict__ out)
{
    int idx = blockIdx.x * blockDim.x + threadIdx.x;
    if (idx >= NT) return;

    constexpr int ZT = Z / VPT;   // 40
    int zq = idx % ZT;
    int t  = idx / ZT;
    int y  = t % Y;
    int t2 = t / Y;
    int x  = t2 % X;
    int b  = t2 / X;
    int z0 = zq * VPT;

    size_t vid = (size_t)idx * VPT;

    // 12 consecutive trf floats (4 voxels x 3), 48B per lane, 16B aligned
    const f32x4* tp = reinterpret_cast<const f32x4*>(trf + vid * 3);
    f32x4 ta = tp[0];
    f32x4 tb = tp[1];
    f32x4 tc = tp[2];
    float d[12] = {ta.x, ta.y, ta.z, ta.w,
                   tb.x, tb.y, tb.z, tb.w,
                   tc.x, tc.y, tc.z, tc.w};

    const float mx = (float)(X - 1), my = (float)(Y - 1), mz = (float)(Z - 1);
    const int bX = b * X;
    const float fx = (float)x, fy = (float)y;

    float res[VPT];
#pragma unroll
    for (int j = 0; j < VPT; ++j) {
        float lx = fx + d[3*j + 0];
        float ly = fy + d[3*j + 1];
        float lz = (float)(z0 + j) + d[3*j + 2];

        // reference semantics: l0=clip(floor(l),0,max); l1=clip(l0+1,0,max);
        // cl=clip(l,0,max); weight(corner0)=l1-cl; weight(corner1)=1-(l1-cl)
        float lx0 = fminf(fmaxf(floorf(lx), 0.0f), mx);
        float lx1 = fminf(lx0 + 1.0f, mx);
        float clx = fminf(fmaxf(lx, 0.0f), mx);
        float wxA = lx1 - clx, wxB = 1.0f - wxA;
        int ix0 = (int)lx0, ix1 = (int)lx1;

        float ly0 = fminf(fmaxf(floorf(ly), 0.0f), my);
        float ly1 = fminf(ly0 + 1.0f, my);
        float cly = fminf(fmaxf(ly, 0.0f), my);
        float wyA = ly1 - cly, wyB = 1.0f - wyA;
        int iy0 = (int)ly0, iy1 = (int)ly1;

        float lz0 = fminf(fmaxf(floorf(lz), 0.0f), mz);
        float lz1 = fminf(lz0 + 1.0f, mz);
        float clz = fminf(fmaxf(lz, 0.0f), mz);
        float wzA = lz1 - clz, wzB = 1.0f - wzA;
        int iz0 = (int)lz0, iz1 = (int)lz1;

        size_t base00 = ((size_t)(bX + ix0) * Y + iy0) * Z;
        size_t base01 = ((size_t)(bX + ix0) * Y + iy1) * Z;
        size_t base10 = ((size_t)(bX + ix1) * Y + iy0) * Z;
        size_t base11 = ((size_t)(bX + ix1) * Y + iy1) * Z;

        float v000 = vol[base00 + iz0];
        float v001 = vol[base00 + iz1];
        float v010 = vol[base01 + iz0];
        float v011 = vol[base01 + iz1];
        float v100 = vol[base10 + iz0];
        float v101 = vol[base10 + iz1];
        float v110 = vol[base11 + iz0];
        float v111 = vol[base11 + iz1];

        res[j] = wxA * (wyA * (wzA * v000 + wzB * v001) +
                        wyB * (wzA * v010 + wzB * v011)) +
                 wxB * (wyA * (wzA * v100 + wzB * v101) +
                        wyB * (wzA * v110 + wzB * v111));
    }

    f32x4 o;
    o.x = res[0]; o.y = res[1]; o.z = res[2]; o.w = res[3];
    __builtin_nontemporal_store(o, reinterpret_cast<f32x4*>(out + vid));
}

extern "C" void kernel_launch(void* const* d_in, const int* in_sizes, int n_in,
                              void* d_out, int out_size, void* d_ws, size_t ws_size,
                              hipStream_t stream) {
    const float* vol = (const float*)d_in[0];
    const float* trf = (const float*)d_in[1];
    float* out = (float*)d_out;

    int threads = 256;
    int blocks = (NT + threads - 1) / threads;
    warp_kernel<<<blocks, threads, 0, stream>>>(vol, trf, out);
}

// Round 4
// 94.267 us; speedup vs baseline: 1.3476x; 1.3476x over previous
//
#include <hip/hip_runtime.h>

// vol [2,160,192,160,1] f32, trf [2,160,192,160,3] f32
constexpr int B = 2, X = 160, Y = 192, Z = 160;
constexpr int N = B * X * Y * Z;      // 9,830,400 = 38400 * 256 exactly
constexpr int NBLK = N / 256;

__global__ __launch_bounds__(256) void warp_kernel(
    const float* __restrict__ vol,
    const float* __restrict__ trf,
    float* __restrict__ out)
{
    __shared__ float s[768];          // 256 voxels x 3 displacement floats

    const int tid = threadIdx.x;
    const size_t base = (size_t)blockIdx.x * 256;   // first voxel of block

    // Coalesced SoA-style load of 768 consecutive trf floats (3 lines/wave/load)
    const float* tf = trf + base * 3;
    s[tid]       = tf[tid];
    s[tid + 256] = tf[tid + 256];
    s[tid + 512] = tf[tid + 512];
    __syncthreads();

    const float dx = s[3 * tid + 0];
    const float dy = s[3 * tid + 1];
    const float dz = s[3 * tid + 2];

    const int idx = (int)base + tid;

    // decompose idx -> (b, x, y, z), z innermost
    int z  = idx % Z;
    int t  = idx / Z;
    int y  = t % Y;
    int t2 = t / Y;
    int x  = t2 % X;
    int b  = t2 / X;

    float lx = (float)x + dx;
    float ly = (float)y + dy;
    float lz = (float)z + dz;

    // reference semantics: l0=clip(floor(l),0,max); l1=clip(l0+1,0,max);
    // cl=clip(l,0,max); weight(corner0)=l1-cl; weight(corner1)=1-(l1-cl)
    const float mx = (float)(X - 1), my = (float)(Y - 1), mz = (float)(Z - 1);

    float lx0 = fminf(fmaxf(floorf(lx), 0.0f), mx);
    float lx1 = fminf(lx0 + 1.0f, mx);
    float clx = fminf(fmaxf(lx, 0.0f), mx);
    float wxA = lx1 - clx, wxB = 1.0f - wxA;
    int ix0 = (int)lx0, ix1 = (int)lx1;

    float ly0 = fminf(fmaxf(floorf(ly), 0.0f), my);
    float ly1 = fminf(ly0 + 1.0f, my);
    float cly = fminf(fmaxf(ly, 0.0f), my);
    float wyA = ly1 - cly, wyB = 1.0f - wyA;
    int iy0 = (int)ly0, iy1 = (int)ly1;

    float lz0 = fminf(fmaxf(floorf(lz), 0.0f), mz);
    float lz1 = fminf(lz0 + 1.0f, mz);
    float clz = fminf(fmaxf(lz, 0.0f), mz);
    float wzA = lz1 - clz, wzB = 1.0f - wzA;
    int iz0 = (int)lz0, iz1 = (int)lz1;

    int bX = b * X;
    size_t base00 = ((size_t)(bX + ix0) * Y + iy0) * Z;
    size_t base01 = ((size_t)(bX + ix0) * Y + iy1) * Z;
    size_t base10 = ((size_t)(bX + ix1) * Y + iy0) * Z;
    size_t base11 = ((size_t)(bX + ix1) * Y + iy1) * Z;

    float v000 = vol[base00 + iz0];
    float v001 = vol[base00 + iz1];
    float v010 = vol[base01 + iz0];
    float v011 = vol[base01 + iz1];
    float v100 = vol[base10 + iz0];
    float v101 = vol[base10 + iz1];
    float v110 = vol[base11 + iz0];
    float v111 = vol[base11 + iz1];

    float r = wxA * (wyA * (wzA * v000 + wzB * v001) +
                     wyB * (wzA * v010 + wzB * v011)) +
              wxB * (wyA * (wzA * v100 + wzB * v101) +
                     wyB * (wzA * v110 + wzB * v111));

    out[idx] = r;
}

extern "C" void kernel_launch(void* const* d_in, const int* in_sizes, int n_in,
                              void* d_out, int out_size, void* d_ws, size_t ws_size,
                              hipStream_t stream) {
    const float* vol = (const float*)d_in[0];
    const float* trf = (const float*)d_in[1];
    float* out = (float*)d_out;

    warp_kernel<<<NBLK, 256, 0, stream>>>(vol, trf, out);
}

// Round 5
// 71.709 us; speedup vs baseline: 1.7715x; 1.3146x over previous
//
#include <hip/hip_runtime.h>

// vol [2,160,192,160,1] f32, trf [2,160,192,160,3] f32
constexpr int B = 2, X = 160, Y = 192, Z = 160;
constexpr int N = B * X * Y * Z;      // 9,830,400 = 38400 * 256 exactly
constexpr int NBLK = N / 256;

typedef float f32x2 __attribute__((ext_vector_type(2), aligned(4)));

__global__ __launch_bounds__(256) void warp_kernel(
    const float* __restrict__ vol,
    const float* __restrict__ trf,
    float* __restrict__ out)
{
    __shared__ float s[768];          // 256 voxels x 3 displacement floats

    const int tid = threadIdx.x;
    const size_t base = (size_t)blockIdx.x * 256;   // first voxel of block

    // coalesced load of this block's 768 consecutive trf floats
    const float* tf = trf + base * 3;
    s[tid]       = tf[tid];
    s[tid + 256] = tf[tid + 256];
    s[tid + 512] = tf[tid + 512];
    __syncthreads();

    const float dx = s[3 * tid + 0];
    const float dy = s[3 * tid + 1];
    const float dz = s[3 * tid + 2];

    const int idx = (int)base + tid;

    // decompose idx -> (b, x, y, z), z innermost
    int z  = idx % Z;
    int t  = idx / Z;
    int y  = t % Y;
    int t2 = t / Y;
    int x  = t2 % X;
    int b  = t2 / X;

    float lx = (float)x + dx;
    float ly = (float)y + dy;
    float lz = (float)z + dz;

    // reference semantics: l0=clip(floor(l),0,max); l1=clip(l0+1,0,max);
    // cl=clip(l,0,max); weight(corner0)=l1-cl; weight(corner1)=1-(l1-cl)
    const float mx = (float)(X - 1), my = (float)(Y - 1), mz = (float)(Z - 1);

    float lx0 = fminf(fmaxf(floorf(lx), 0.0f), mx);
    float lx1 = fminf(lx0 + 1.0f, mx);
    float clx = fminf(fmaxf(lx, 0.0f), mx);
    float wxA = lx1 - clx, wxB = 1.0f - wxA;
    int ix0 = (int)lx0, ix1 = (int)lx1;

    float ly0 = fminf(fmaxf(floorf(ly), 0.0f), my);
    float ly1 = fminf(ly0 + 1.0f, my);
    float cly = fminf(fmaxf(ly, 0.0f), my);
    float wyA = ly1 - cly, wyB = 1.0f - wyA;
    int iy0 = (int)ly0, iy1 = (int)ly1;

    float lz0 = fminf(fmaxf(floorf(lz), 0.0f), mz);
    float lz1 = fminf(lz0 + 1.0f, mz);
    float clz = fminf(fmaxf(lz, 0.0f), mz);
    float wzA = lz1 - clz, wzB = 1.0f - wzA;
    int iz0 = (int)lz0;

    // z-pair gather: one 8B load covers both z corners.
    // pz = min(iz0, Z-2); iz0==pz ? (v0,v1)=(p.x,p.y) : (v0,v1)=(p.y,p.y)
    // (iz0 > pz only when iz0 == Z-1, where iz1 == iz0 == Z-1 too)
    int pz = min(iz0, Z - 2);
    bool hi = (iz0 != pz);

    int bX = b * X;
    size_t base00 = ((size_t)(bX + ix0) * Y + iy0) * Z + pz;
    size_t base01 = ((size_t)(bX + ix0) * Y + iy1) * Z + pz;
    size_t base10 = ((size_t)(bX + ix1) * Y + iy0) * Z + pz;
    size_t base11 = ((size_t)(bX + ix1) * Y + iy1) * Z + pz;

    f32x2 p00 = *reinterpret_cast<const f32x2*>(vol + base00);
    f32x2 p01 = *reinterpret_cast<const f32x2*>(vol + base01);
    f32x2 p10 = *reinterpret_cast<const f32x2*>(vol + base10);
    f32x2 p11 = *reinterpret_cast<const f32x2*>(vol + base11);

    float v000 = hi ? p00.y : p00.x, v001 = p00.y;
    float v010 = hi ? p01.y : p01.x, v011 = p01.y;
    float v100 = hi ? p10.y : p10.x, v101 = p10.y;
    float v110 = hi ? p11.y : p11.x, v111 = p11.y;

    float r = wxA * (wyA * (wzA * v000 + wzB * v001) +
                     wyB * (wzA * v010 + wzB * v011)) +
              wxB * (wyA * (wzA * v100 + wzB * v101) +
                     wyB * (wzA * v110 + wzB * v111));

    out[idx] = r;
}

extern "C" void kernel_launch(void* const* d_in, const int* in_sizes, int n_in,
                              void* d_out, int out_size, void* d_ws, size_t ws_size,
                              hipStream_t stream) {
    const float* vol = (const float*)d_in[0];
    const float* trf = (const float*)d_in[1];
    float* out = (float*)d_out;

    warp_kernel<<<NBLK, 256, 0, stream>>>(vol, trf, out);
}